// Round 4
// baseline (757.685 us; speedup 1.0000x reference)
//
#include <hip/hip_runtime.h>
#include <hip/hip_bf16.h>

// Bahdanau attention, MI355X. B=32, T=2048, D=1024, U=1024.
// R4: score GEMM moved to mfma_f32_32x32x16_bf16 (2495 TF pipe vs 2176,
// half the issue slots). init_kernel removed (memsetAsync + non-atomic
// projq with fused bias). Swizzle + glls16 staging from R3 kept.

typedef __bf16 bf16x8 __attribute__((ext_vector_type(8)));
typedef __bf16 bf16x4 __attribute__((ext_vector_type(4)));
typedef float  f32x4  __attribute__((ext_vector_type(4)));
typedef float  f32x16 __attribute__((ext_vector_type(16)));

#define B_  32
#define T_  2048
#define D_  1024
#define U_  1024
#define BT_ (B_*T_)

// ws layout (bytes)
#define WS_W1T    ((size_t)0)                          // 2 MiB bf16 [U][D]
#define WS_PROJQ  ((size_t)(2u*1024*1024))             // 128 KiB fp32 [B][U]
#define WS_SCORE  ((size_t)(2u*1024*1024 + 128u*1024)) // 256 KiB fp32 [B*T]
#define WS_VALB   ((size_t)(4u*1024*1024))             // 128 MiB bf16 [BT][D]
#define WS_NEEDED (WS_VALB + (size_t)BT_ * D_ * 2)

__device__ __forceinline__ float tanh_fast(float x) {
    const float e = __expf(2.0f * x);
    return 1.0f - __fdividef(2.0f, e + 1.0f);
}

__device__ __forceinline__ void glls16(const void* g, void* l) {
    __builtin_amdgcn_global_load_lds(
        (const __attribute__((address_space(1))) void*)g,
        (__attribute__((address_space(3))) void*)l, 16, 0, 0);
}

// ---------------- values fp32 -> bf16 (streaming) ----------------
__global__ void convert_kernel(const float* __restrict__ v, __bf16* __restrict__ o) {
    const size_t i = ((size_t)blockIdx.x * 256 + threadIdx.x) * 8;   // grid 32768
    const float4 a = *(const float4*)(v + i);
    const float4 b = *(const float4*)(v + i + 4);
    bf16x8 h;
    h[0] = (__bf16)a.x; h[1] = (__bf16)a.y; h[2] = (__bf16)a.z; h[3] = (__bf16)a.w;
    h[4] = (__bf16)b.x; h[5] = (__bf16)b.y; h[6] = (__bf16)b.z; h[7] = (__bf16)b.w;
    *(bf16x8*)(o + i) = h;
}

// ---------------- W1 [D][U] fp32 -> W1T [U][D] bf16 ----------------
__global__ void w1_transpose_kernel(const float* __restrict__ W1, __bf16* __restrict__ W1T) {
    __shared__ float tile[64][65];
    const int bx = blockIdx.x & 15;   // u tile
    const int by = blockIdx.x >> 4;   // d tile
    const int tid = threadIdx.x;      // 256
    const int j  = tid & 63;
    const int i0 = tid >> 6;          // 0..3
#pragma unroll
    for (int p = 0; p < 16; ++p) {
        const int i = i0 + p * 4;
        tile[i][j] = W1[(size_t)(by * 64 + i) * U_ + bx * 64 + j];
    }
    __syncthreads();
#pragma unroll
    for (int p = 0; p < 16; ++p) {
        const int i = i0 + p * 4;     // local u row
        W1T[(size_t)(bx * 64 + i) * D_ + by * 64 + j] = (__bf16)tile[j][i];
    }
}

// ---------------- projq = b1 + b2 + query @ W2 (non-atomic, fused bias) ----
// grid 64: blockIdx = b*2 + uc. Thread owns 2 consecutive u (float2).
__global__ void projq_kernel(const float* __restrict__ query, const float* __restrict__ W2,
                             const float* __restrict__ b1, const float* __restrict__ b2,
                             float* __restrict__ projq) {
    __shared__ float q[D_];
    const int b  = blockIdx.x >> 1;
    const int uc = blockIdx.x & 1;
    const int tid = threadIdx.x;      // 256
    *(float4*)(q + tid * 4) = *(const float4*)(query + (size_t)b * D_ + tid * 4);
    __syncthreads();
    const int u0 = uc * 512 + tid * 2;
    float a0 = b1[u0] + b2[u0];
    float a1 = b1[u0 + 1] + b2[u0 + 1];
#pragma unroll 8
    for (int d = 0; d < D_; ++d) {
        const float2 w = *(const float2*)(W2 + (size_t)d * U_ + u0);
        const float qd = q[d];
        a0 = fmaf(qd, w.x, a0);
        a1 = fmaf(qd, w.y, a1);
    }
    *(float2*)(projq + (size_t)b * U_ + u0) = make_float2(a0, a1);
}

// ---------------- fused score GEMM, 32x32x16 MFMA ----------------
// grid 4096, XCD swizzle (R3). 256 threads = 4 waves, wave tile 64x64 =
// 2x2 of 32x32 MFMA blocks. Tile 128(bt) x 128(u), BK=32.
// LDS [128][32] bf16 (64B rows), glls16 staging (R3-proven).
__global__ __launch_bounds__(256, 3)
void score_kernel_bf16(const __bf16* __restrict__ valb, const __bf16* __restrict__ W1T,
                       const float* __restrict__ projq, const float* __restrict__ V,
                       float* __restrict__ score) {
    __shared__ __attribute__((aligned(16))) __bf16 Al[128 * 32];
    __shared__ __attribute__((aligned(16))) __bf16 Bl[128 * 32];

    const int tid = threadIdx.x;
    const int xcd  = blockIdx.x & 7;
    const int slot = blockIdx.x >> 3;
    const int rowblk = xcd * 64 + (slot >> 3);
    const int utile  = slot & 7;
    const int wave = tid >> 6, lane = tid & 63;
    const int l31 = lane & 31, half = lane >> 5;
    const int wr = (wave >> 1) * 64;   // wave row offset in tile
    const int wc = (wave & 1) * 64;    // wave col offset in tile

    const __bf16* Ab = valb + ((size_t)rowblk * 128 + (tid >> 2)) * D_ + (tid & 3) * 8;
    const __bf16* Bb = W1T + ((size_t)utile * 128 + (tid >> 2)) * D_ + (tid & 3) * 8;
    __bf16* Ald = Al + wave * 512;     // wave-uniform LDS base
    __bf16* Bld = Bl + wave * 512;

    f32x16 acc[2][2];
#pragma unroll
    for (int i = 0; i < 2; ++i)
#pragma unroll
        for (int j = 0; j < 2; ++j)
#pragma unroll
            for (int r = 0; r < 16; ++r)
                acc[i][j][r] = 0.f;

    for (int kk = 0; kk < D_; kk += 32) {
        glls16(Ab + kk,            Ald);
        glls16(Ab + 64 * D_ + kk,  Ald + 2048);
        glls16(Bb + kk,            Bld);
        glls16(Bb + 64 * D_ + kk,  Bld + 2048);
        __syncthreads();

        // A/B frags: 8 contiguous k-elems per lane: [m=l31][k=half*8+j+ks*16]
        bf16x8 af[2][2], bfr[2][2];
#pragma unroll
        for (int mb = 0; mb < 2; ++mb)
#pragma unroll
            for (int ks = 0; ks < 2; ++ks)
                af[mb][ks] = *(const bf16x8*)(Al + (wr + mb * 32 + l31) * 32 + ks * 16 + half * 8);
#pragma unroll
        for (int nb = 0; nb < 2; ++nb)
#pragma unroll
            for (int ks = 0; ks < 2; ++ks)
                bfr[nb][ks] = *(const bf16x8*)(Bl + (wc + nb * 32 + l31) * 32 + ks * 16 + half * 8);
#pragma unroll
        for (int mb = 0; mb < 2; ++mb)
#pragma unroll
            for (int nb = 0; nb < 2; ++nb)
#pragma unroll
                for (int ks = 0; ks < 2; ++ks)
                    acc[mb][nb] = __builtin_amdgcn_mfma_f32_32x32x16_bf16(
                        af[mb][ks], bfr[nb][ks], acc[mb][nb], 0, 0, 0);
        __syncthreads();
    }

    // epilogue: partial score = sum_u tanh(acc + projq[b][u]) * V[u]
    // C/D layout: col = lane&31, row = (r&3) + 8*(r>>2) + 4*half  [m74/m101]
    const int b = rowblk >> 4;                 // 16 rowblks (of 128) per batch
    const float* pq = projq + (size_t)b * U_ + utile * 128 + wc;
    const float* Vp = V + utile * 128 + wc;
    const size_t rowbase = (size_t)rowblk * 128 + wr;
#pragma unroll
    for (int mb = 0; mb < 2; ++mb) {
        float s[16];
#pragma unroll
        for (int r = 0; r < 16; ++r) s[r] = 0.f;
#pragma unroll
        for (int nb = 0; nb < 2; ++nb) {
            const int u = nb * 32 + l31;
            const float pqu = pq[u];
            const float vu  = Vp[u];
#pragma unroll
            for (int r = 0; r < 16; ++r)
                s[r] += tanh_fast(acc[mb][nb][r] + pqu) * vu;
        }
#pragma unroll
        for (int r = 0; r < 16; ++r) {
            float v = s[r];
            v += __shfl_xor(v, 1);
            v += __shfl_xor(v, 2);
            v += __shfl_xor(v, 4);
            v += __shfl_xor(v, 8);
            v += __shfl_xor(v, 16);
            if (l31 == 0) {
                const int row = mb * 32 + (r & 3) + 8 * (r >> 2) + 4 * half;
                atomicAdd(&score[rowbase + row], v);
            }
        }
    }
}

// ---------------- fallback score GEMM (fp32 staging), if ws too small ----
__global__ __launch_bounds__(512, 2)
void score_kernel_f32(const float* __restrict__ values, const __bf16* __restrict__ W1T,
                      const float* __restrict__ projq, const float* __restrict__ V,
                      float* __restrict__ score) {
    __shared__ __attribute__((aligned(16))) __bf16 Al[64][40];
    __shared__ __attribute__((aligned(16))) __bf16 Bl[512][40];
    const int tid    = threadIdx.x;
    const int rowblk = blockIdx.x >> 1;
    const int nhalf  = blockIdx.x & 1;
    const int wave = tid >> 6, lane = tid & 63;
    const int quad = lane >> 4, l15 = lane & 15;
    const float*  Abase = values + (size_t)rowblk * 64 * D_;
    const __bf16* Bbase = W1T + (size_t)nhalf * 512 * D_;
    const int ar = tid >> 3, ac = (tid & 7) * 4;
    const int br = tid >> 2, bc = (tid & 3) * 8;
    f32x4 acc[4][4];
#pragma unroll
    for (int i = 0; i < 4; ++i)
#pragma unroll
        for (int j = 0; j < 4; ++j) { f32x4 z = {0.f,0.f,0.f,0.f}; acc[i][j] = z; }
    for (int kk = 0; kk < D_; kk += 32) {
        {
            const float4 v = *(const float4*)(Abase + (size_t)ar * D_ + kk + ac);
            bf16x4 h;
            h[0] = (__bf16)v.x; h[1] = (__bf16)v.y; h[2] = (__bf16)v.z; h[3] = (__bf16)v.w;
            *(bf16x4*)(&Al[ar][ac]) = h;
        }
#pragma unroll
        for (int p = 0; p < 4; ++p) {
            const int rr = p * 128 + br;
            const bf16x8 w = *(const bf16x8*)(Bbase + (size_t)rr * D_ + kk + bc);
            *(bf16x8*)(&Bl[rr][bc]) = w;
        }
        __syncthreads();
        bf16x8 af[4];
#pragma unroll
        for (int mt = 0; mt < 4; ++mt)
            af[mt] = *(const bf16x8*)(&Al[mt * 16 + l15][quad * 8]);
#pragma unroll
        for (int nt = 0; nt < 4; ++nt) {
            const bf16x8 bfr = *(const bf16x8*)(&Bl[wave * 64 + nt * 16 + l15][quad * 8]);
#pragma unroll
            for (int mt = 0; mt < 4; ++mt)
                acc[mt][nt] = __builtin_amdgcn_mfma_f32_16x16x32_bf16(af[mt], bfr, acc[mt][nt], 0, 0, 0);
        }
        __syncthreads();
    }
    const int b = rowblk >> 5;
    const size_t rowbase = (size_t)rowblk * 64;
    const float* pq = projq + (size_t)b * U_;
    const int ub = nhalf * 512 + wave * 64;
#pragma unroll
    for (int mt = 0; mt < 4; ++mt) {
        float s0 = 0.f, s1 = 0.f, s2 = 0.f, s3 = 0.f;
#pragma unroll
        for (int nt = 0; nt < 4; ++nt) {
            const int u = ub + nt * 16 + l15;
            const float pqu = pq[u];
            const float vu  = V[u];
            s0 += tanh_fast(acc[mt][nt][0] + pqu) * vu;
            s1 += tanh_fast(acc[mt][nt][1] + pqu) * vu;
            s2 += tanh_fast(acc[mt][nt][2] + pqu) * vu;
            s3 += tanh_fast(acc[mt][nt][3] + pqu) * vu;
        }
        float s[4] = {s0, s1, s2, s3};
#pragma unroll
        for (int r = 0; r < 4; ++r) {
            float v = s[r];
            v += __shfl_xor(v, 1);
            v += __shfl_xor(v, 2);
            v += __shfl_xor(v, 4);
            v += __shfl_xor(v, 8);
            if (l15 == 0)
                atomicAdd(&score[rowbase + mt * 16 + quad * 4 + r], v);
        }
    }
}

// ---------------- softmax over T (masked), writes attention weights ----------------
__global__ void softmax_kernel(const float* __restrict__ score, const float* __restrict__ mask,
                               const float* __restrict__ bV, float* __restrict__ out) {
    const int b = blockIdx.x;     // 32
    const int tid = threadIdx.x;  // 256
    const float bv = bV[0];
    float s[8];
    float lmax = -3.0e38f;
#pragma unroll
    for (int i = 0; i < 8; ++i) {
        const int t = tid + i * 256;
        const float v = score[(size_t)b * T_ + t] + bv + mask[(size_t)b * T_ + t] * (-1.0e9f);
        s[i] = v;
        lmax = fmaxf(lmax, v);
    }
#pragma unroll
    for (int m = 1; m < 64; m <<= 1) lmax = fmaxf(lmax, __shfl_xor(lmax, m));
    __shared__ float redm[4], reds[4];
    if ((tid & 63) == 0) redm[tid >> 6] = lmax;
    __syncthreads();
    const float M = fmaxf(fmaxf(redm[0], redm[1]), fmaxf(redm[2], redm[3]));
    float lsum = 0.f;
#pragma unroll
    for (int i = 0; i < 8; ++i) { s[i] = __expf(s[i] - M); lsum += s[i]; }
#pragma unroll
    for (int m = 1; m < 64; m <<= 1) lsum += __shfl_xor(lsum, m);
    if ((tid & 63) == 0) reds[tid >> 6] = lsum;
    __syncthreads();
    const float inv = 1.0f / (reds[0] + reds[1] + reds[2] + reds[3]);
#pragma unroll
    for (int i = 0; i < 8; ++i)
        out[(size_t)B_ * D_ + (size_t)b * T_ + tid + i * 256] = s[i] * inv;
}

// ---------------- context = sum_t attn[b,t] * values[b,t,:] ----------------
__global__ void context_kernel(const float* __restrict__ values, const float* __restrict__ attn,
                               float* __restrict__ out) {
    const int b  = blockIdx.x >> 4;   // 32
    const int dc = blockIdx.x & 15;   // 16 chunks of 64 d
    const int tid = threadIdx.x;      // 256
    __shared__ float a[T_];
#pragma unroll
    for (int i = 0; i < 8; ++i) a[tid + i * 256] = attn[(size_t)b * T_ + tid + i * 256];
    __syncthreads();
    const int dl = (tid & 15) * 4;    // 64 d per block, float4 per thread
    const int tg = tid >> 4;          // 0..15
    const float* vb = values + (size_t)b * T_ * D_ + dc * 64 + dl;
    f32x4 acc = {0.f, 0.f, 0.f, 0.f};
#pragma unroll 4
    for (int t = tg; t < T_; t += 16) {
        const float4 v = *(const float4*)(vb + (size_t)t * D_);
        const float w = a[t];
        acc[0] = fmaf(w, v.x, acc[0]);
        acc[1] = fmaf(w, v.y, acc[1]);
        acc[2] = fmaf(w, v.z, acc[2]);
        acc[3] = fmaf(w, v.w, acc[3]);
    }
    __shared__ __attribute__((aligned(16))) float red[16][64];
    *(f32x4*)(&red[tg][dl]) = acc;
    __syncthreads();
    if (tid < 64) {
        float s = 0.f;
#pragma unroll
        for (int g = 0; g < 16; ++g) s += red[g][tid];
        out[(size_t)b * D_ + dc * 64 + tid] = s;
    }
}

extern "C" void kernel_launch(void* const* d_in, const int* in_sizes, int n_in,
                              void* d_out, int out_size, void* d_ws, size_t ws_size,
                              hipStream_t stream) {
    const float* values = (const float*)d_in[0];
    const float* query  = (const float*)d_in[1];
    const float* mask   = (const float*)d_in[2];
    const float* W1     = (const float*)d_in[3];
    const float* b1     = (const float*)d_in[4];
    const float* W2     = (const float*)d_in[5];
    const float* b2     = (const float*)d_in[6];
    const float* V      = (const float*)d_in[7];
    const float* bV     = (const float*)d_in[8];
    float* out = (float*)d_out;

    char* ws = (char*)d_ws;
    __bf16* W1T   = (__bf16*)(ws + WS_W1T);
    float*  projq = (float*)(ws + WS_PROJQ);
    float*  score = (float*)(ws + WS_SCORE);
    __bf16* valb  = (__bf16*)(ws + WS_VALB);

    hipMemsetAsync(score, 0, (size_t)BT_ * sizeof(float), stream);
    w1_transpose_kernel<<<dim3(256), dim3(256), 0, stream>>>(W1, W1T);
    projq_kernel<<<dim3(64), dim3(256), 0, stream>>>(query, W2, b1, b2, projq);
    if (ws_size >= WS_NEEDED) {
        convert_kernel<<<dim3(32768), dim3(256), 0, stream>>>(values, valb);
        score_kernel_bf16<<<dim3(4096), dim3(256), 0, stream>>>(valb, W1T, projq, V, score);
    } else {
        score_kernel_f32<<<dim3(2048), dim3(512), 0, stream>>>(values, W1T, projq, V, score);
    }
    softmax_kernel<<<dim3(32), dim3(256), 0, stream>>>(score, mask, bV, out);
    context_kernel<<<dim3(512), dim3(256), 0, stream>>>(values, out + B_ * D_, out);
}

// Round 5
// 691.567 us; speedup vs baseline: 1.0956x; 1.0956x over previous
//
#include <hip/hip_runtime.h>
#include <hip/hip_bf16.h>

// Bahdanau attention, MI355X. B=32, T=2048, D=1024, U=1024.
// R5: score reverted to R3 16x16x32 (R4's 32x32 frag reads = 3x bank
// conflicts). Context rewritten 2-stage, 1024-block, full-row coalesced
// (old version: 2 blocks/CU, ~0.8 TB/s suspected ~300us elephant).

typedef __bf16 bf16x8 __attribute__((ext_vector_type(8)));
typedef __bf16 bf16x4 __attribute__((ext_vector_type(4)));
typedef float  f32x4  __attribute__((ext_vector_type(4)));

#define B_  32
#define T_  2048
#define D_  1024
#define U_  1024
#define BT_ (B_*T_)

// ws layout (bytes)
#define WS_W1T    ((size_t)0)                          // 2 MiB bf16 [U][D]
#define WS_PROJQ  ((size_t)(2u*1024*1024))             // 128 KiB fp32 [B][U]
#define WS_SCORE  ((size_t)(2u*1024*1024 + 128u*1024)) // 256 KiB fp32 [B*T]
// context partials [32 tc][32 b][1024 d] fp32 = 4 MiB. Reuses [0,4MiB):
// W1T/projq/score are all dead by the time context1 runs (after softmax).
#define WS_CTXP   ((size_t)0)
#define WS_VALB   ((size_t)(4u*1024*1024))             // 128 MiB bf16 [BT][D]
#define WS_NEEDED (WS_VALB + (size_t)BT_ * D_ * 2)

__device__ __forceinline__ float tanh_fast(float x) {
    const float e = __expf(2.0f * x);
    return 1.0f - __fdividef(2.0f, e + 1.0f);
}

__device__ __forceinline__ void glls16(const void* g, void* l) {
    __builtin_amdgcn_global_load_lds(
        (const __attribute__((address_space(1))) void*)g,
        (__attribute__((address_space(3))) void*)l, 16, 0, 0);
}

// ---------------- values fp32 -> bf16 (streaming) ----------------
__global__ void convert_kernel(const float* __restrict__ v, __bf16* __restrict__ o) {
    const size_t i = ((size_t)blockIdx.x * 256 + threadIdx.x) * 8;   // grid 32768
    const float4 a = *(const float4*)(v + i);
    const float4 b = *(const float4*)(v + i + 4);
    bf16x8 h;
    h[0] = (__bf16)a.x; h[1] = (__bf16)a.y; h[2] = (__bf16)a.z; h[3] = (__bf16)a.w;
    h[4] = (__bf16)b.x; h[5] = (__bf16)b.y; h[6] = (__bf16)b.z; h[7] = (__bf16)b.w;
    *(bf16x8*)(o + i) = h;
}

// ---------------- W1 [D][U] fp32 -> W1T [U][D] bf16 ----------------
__global__ void w1_transpose_kernel(const float* __restrict__ W1, __bf16* __restrict__ W1T) {
    __shared__ float tile[64][65];
    const int bx = blockIdx.x & 15;   // u tile
    const int by = blockIdx.x >> 4;   // d tile
    const int tid = threadIdx.x;      // 256
    const int j  = tid & 63;
    const int i0 = tid >> 6;          // 0..3
#pragma unroll
    for (int p = 0; p < 16; ++p) {
        const int i = i0 + p * 4;
        tile[i][j] = W1[(size_t)(by * 64 + i) * U_ + bx * 64 + j];
    }
    __syncthreads();
#pragma unroll
    for (int p = 0; p < 16; ++p) {
        const int i = i0 + p * 4;     // local u row
        W1T[(size_t)(bx * 64 + i) * D_ + by * 64 + j] = (__bf16)tile[j][i];
    }
}

// ---------------- projq = b1 + b2 + query @ W2 (non-atomic, fused bias) ----
// grid 128: blockIdx = b*4 + uc. One u per thread.
__global__ void projq_kernel(const float* __restrict__ query, const float* __restrict__ W2,
                             const float* __restrict__ b1, const float* __restrict__ b2,
                             float* __restrict__ projq) {
    __shared__ float q[D_];
    const int b  = blockIdx.x >> 2;
    const int uc = blockIdx.x & 3;
    const int tid = threadIdx.x;      // 256
    *(float4*)(q + tid * 4) = *(const float4*)(query + (size_t)b * D_ + tid * 4);
    __syncthreads();
    const int u0 = uc * 256 + tid;
    float a0 = b1[u0] + b2[u0];
#pragma unroll 8
    for (int d = 0; d < D_; ++d)
        a0 = fmaf(q[d], W2[(size_t)d * U_ + u0], a0);
    projq[(size_t)b * U_ + u0] = a0;
}

// ---------------- fused score GEMM (R3 config: 16x16x32, XCD swizzle) -------
// grid 4096. xcd = blk&7, slot = blk>>3; rowblk = xcd*64 + (slot>>3),
// utile = slot&7 -> A-tile sharers co-XCD, adjacent. 256 thr = 4 waves
// (2x2 of 64x64 wave tiles). Tile 128(bt) x 128(u), BK=32.
// LDS unpadded [128][32] bf16: frag b128 reads bank-clean (quad*16 spread).
__global__ __launch_bounds__(256, 3)
void score_kernel_bf16(const __bf16* __restrict__ valb, const __bf16* __restrict__ W1T,
                       const float* __restrict__ projq, const float* __restrict__ V,
                       float* __restrict__ score) {
    __shared__ __attribute__((aligned(16))) __bf16 Al[128 * 32];
    __shared__ __attribute__((aligned(16))) __bf16 Bl[128 * 32];

    const int tid = threadIdx.x;
    const int xcd  = blockIdx.x & 7;
    const int slot = blockIdx.x >> 3;
    const int rowblk = xcd * 64 + (slot >> 3);
    const int utile  = slot & 7;
    const int wave = tid >> 6, lane = tid & 63;
    const int quad = lane >> 4, l15 = lane & 15;
    const int wr = (wave >> 1) * 64;   // wave row offset in tile
    const int wc = (wave & 1) * 64;    // wave col offset in tile

    const __bf16* Ab = valb + ((size_t)rowblk * 128 + (tid >> 2)) * D_ + (tid & 3) * 8;
    const __bf16* Bb = W1T + ((size_t)utile * 128 + (tid >> 2)) * D_ + (tid & 3) * 8;
    __bf16* Ald = Al + wave * 512;     // wave-uniform LDS base
    __bf16* Bld = Bl + wave * 512;

    f32x4 acc[4][4];
#pragma unroll
    for (int i = 0; i < 4; ++i)
#pragma unroll
        for (int j = 0; j < 4; ++j) {
            f32x4 z = {0.f, 0.f, 0.f, 0.f};
            acc[i][j] = z;
        }

    for (int kk = 0; kk < D_; kk += 32) {
        glls16(Ab + kk,            Ald);
        glls16(Ab + 64 * D_ + kk,  Ald + 2048);
        glls16(Bb + kk,            Bld);
        glls16(Bb + 64 * D_ + kk,  Bld + 2048);
        __syncthreads();

        bf16x8 af[4];
#pragma unroll
        for (int mt = 0; mt < 4; ++mt)
            af[mt] = *(const bf16x8*)(Al + (wr + mt * 16 + l15) * 32 + quad * 8);
#pragma unroll
        for (int nt = 0; nt < 4; ++nt) {
            const bf16x8 bfr = *(const bf16x8*)(Bl + (wc + nt * 16 + l15) * 32 + quad * 8);
#pragma unroll
            for (int mt = 0; mt < 4; ++mt)
                acc[mt][nt] = __builtin_amdgcn_mfma_f32_16x16x32_bf16(af[mt], bfr, acc[mt][nt], 0, 0, 0);
        }
        __syncthreads();
    }

    // epilogue: partial score = sum_u tanh(acc + projq[b][u]) * V[u]
    const int b = rowblk >> 4;                 // 16 rowblks (of 128) per batch
    const float* pq = projq + (size_t)b * U_ + utile * 128 + wc;
    const float* Vp = V + utile * 128 + wc;
    const size_t rowbase = (size_t)rowblk * 128 + wr;
#pragma unroll
    for (int mt = 0; mt < 4; ++mt) {
        float s0 = 0.f, s1 = 0.f, s2 = 0.f, s3 = 0.f;
#pragma unroll
        for (int nt = 0; nt < 4; ++nt) {
            const int u = nt * 16 + l15;
            const float pqu = pq[u];
            const float vu  = Vp[u];
            s0 += tanh_fast(acc[mt][nt][0] + pqu) * vu;
            s1 += tanh_fast(acc[mt][nt][1] + pqu) * vu;
            s2 += tanh_fast(acc[mt][nt][2] + pqu) * vu;
            s3 += tanh_fast(acc[mt][nt][3] + pqu) * vu;
        }
        float s[4] = {s0, s1, s2, s3};
#pragma unroll
        for (int r = 0; r < 4; ++r) {
            float v = s[r];
            v += __shfl_xor(v, 1);
            v += __shfl_xor(v, 2);
            v += __shfl_xor(v, 4);
            v += __shfl_xor(v, 8);
            if (l15 == 0)
                atomicAdd(&score[rowbase + mt * 16 + quad * 4 + r], v);
        }
    }
}

// ---------------- fallback score GEMM (fp32 staging), if ws too small ----
__global__ __launch_bounds__(512, 2)
void score_kernel_f32(const float* __restrict__ values, const __bf16* __restrict__ W1T,
                      const float* __restrict__ projq, const float* __restrict__ V,
                      float* __restrict__ score) {
    __shared__ __attribute__((aligned(16))) __bf16 Al[64][40];
    __shared__ __attribute__((aligned(16))) __bf16 Bl[512][40];
    const int tid    = threadIdx.x;
    const int rowblk = blockIdx.x >> 1;
    const int nhalf  = blockIdx.x & 1;
    const int wave = tid >> 6, lane = tid & 63;
    const int quad = lane >> 4, l15 = lane & 15;
    const float*  Abase = values + (size_t)rowblk * 64 * D_;
    const __bf16* Bbase = W1T + (size_t)nhalf * 512 * D_;
    const int ar = tid >> 3, ac = (tid & 7) * 4;
    const int br = tid >> 2, bc = (tid & 3) * 8;
    f32x4 acc[4][4];
#pragma unroll
    for (int i = 0; i < 4; ++i)
#pragma unroll
        for (int j = 0; j < 4; ++j) { f32x4 z = {0.f,0.f,0.f,0.f}; acc[i][j] = z; }
    for (int kk = 0; kk < D_; kk += 32) {
        {
            const float4 v = *(const float4*)(Abase + (size_t)ar * D_ + kk + ac);
            bf16x4 h;
            h[0] = (__bf16)v.x; h[1] = (__bf16)v.y; h[2] = (__bf16)v.z; h[3] = (__bf16)v.w;
            *(bf16x4*)(&Al[ar][ac]) = h;
        }
#pragma unroll
        for (int p = 0; p < 4; ++p) {
            const int rr = p * 128 + br;
            const bf16x8 w = *(const bf16x8*)(Bbase + (size_t)rr * D_ + kk + bc);
            *(bf16x8*)(&Bl[rr][bc]) = w;
        }
        __syncthreads();
        bf16x8 af[4];
#pragma unroll
        for (int mt = 0; mt < 4; ++mt)
            af[mt] = *(const bf16x8*)(&Al[mt * 16 + l15][quad * 8]);
#pragma unroll
        for (int nt = 0; nt < 4; ++nt) {
            const bf16x8 bfr = *(const bf16x8*)(&Bl[wave * 64 + nt * 16 + l15][quad * 8]);
#pragma unroll
            for (int mt = 0; mt < 4; ++mt)
                acc[mt][nt] = __builtin_amdgcn_mfma_f32_16x16x32_bf16(af[mt], bfr, acc[mt][nt], 0, 0, 0);
        }
        __syncthreads();
    }
    const int b = rowblk >> 5;
    const size_t rowbase = (size_t)rowblk * 64;
    const float* pq = projq + (size_t)b * U_;
    const int ub = nhalf * 512 + wave * 64;
#pragma unroll
    for (int mt = 0; mt < 4; ++mt) {
        float s0 = 0.f, s1 = 0.f, s2 = 0.f, s3 = 0.f;
#pragma unroll
        for (int nt = 0; nt < 4; ++nt) {
            const int u = ub + nt * 16 + l15;
            const float pqu = pq[u];
            const float vu  = V[u];
            s0 += tanh_fast(acc[mt][nt][0] + pqu) * vu;
            s1 += tanh_fast(acc[mt][nt][1] + pqu) * vu;
            s2 += tanh_fast(acc[mt][nt][2] + pqu) * vu;
            s3 += tanh_fast(acc[mt][nt][3] + pqu) * vu;
        }
        float s[4] = {s0, s1, s2, s3};
#pragma unroll
        for (int r = 0; r < 4; ++r) {
            float v = s[r];
            v += __shfl_xor(v, 1);
            v += __shfl_xor(v, 2);
            v += __shfl_xor(v, 4);
            v += __shfl_xor(v, 8);
            if (l15 == 0)
                atomicAdd(&score[rowbase + mt * 16 + quad * 4 + r], v);
        }
    }
}

// ---------------- softmax over T (masked), writes attention weights ----------------
__global__ void softmax_kernel(const float* __restrict__ score, const float* __restrict__ mask,
                               const float* __restrict__ bV, float* __restrict__ out) {
    const int b = blockIdx.x;     // 32
    const int tid = threadIdx.x;  // 256
    const float bv = bV[0];
    float s[8];
    float lmax = -3.0e38f;
#pragma unroll
    for (int i = 0; i < 8; ++i) {
        const int t = tid + i * 256;
        const float v = score[(size_t)b * T_ + t] + bv + mask[(size_t)b * T_ + t] * (-1.0e9f);
        s[i] = v;
        lmax = fmaxf(lmax, v);
    }
#pragma unroll
    for (int m = 1; m < 64; m <<= 1) lmax = fmaxf(lmax, __shfl_xor(lmax, m));
    __shared__ float redm[4], reds[4];
    if ((tid & 63) == 0) redm[tid >> 6] = lmax;
    __syncthreads();
    const float M = fmaxf(fmaxf(redm[0], redm[1]), fmaxf(redm[2], redm[3]));
    float lsum = 0.f;
#pragma unroll
    for (int i = 0; i < 8; ++i) { s[i] = __expf(s[i] - M); lsum += s[i]; }
#pragma unroll
    for (int m = 1; m < 64; m <<= 1) lsum += __shfl_xor(lsum, m);
    if ((tid & 63) == 0) reds[tid >> 6] = lsum;
    __syncthreads();
    const float inv = 1.0f / (reds[0] + reds[1] + reds[2] + reds[3]);
#pragma unroll
    for (int i = 0; i < 8; ++i)
        out[(size_t)B_ * D_ + (size_t)b * T_ + tid + i * 256] = s[i] * inv;
}

// ---------------- context stage 1: partial sums over 64-t chunks ----------
// grid 1024: blockIdx = b*32 + tc. Block reads 64 full 4KB rows, perfectly
// coalesced (256 thr x float4 = one row per iteration). ctxp[tc][b][d].
__global__ __launch_bounds__(256)
void context1_kernel(const float* __restrict__ values, const float* __restrict__ attn,
                     float* __restrict__ ctxp) {
    const int b  = blockIdx.x >> 5;
    const int tc = blockIdx.x & 31;
    const int tid = threadIdx.x;      // 256
    __shared__ float sa[64];
    if (tid < 64) sa[tid] = attn[(size_t)b * T_ + tc * 64 + tid];
    __syncthreads();
    const int d0 = tid * 4;
    const float* vb = values + ((size_t)b * T_ + tc * 64) * D_ + d0;
    f32x4 acc = {0.f, 0.f, 0.f, 0.f};
#pragma unroll 8
    for (int t = 0; t < 64; ++t) {
        const float4 v = *(const float4*)(vb + (size_t)t * D_);
        const float w = sa[t];
        acc[0] = fmaf(w, v.x, acc[0]);
        acc[1] = fmaf(w, v.y, acc[1]);
        acc[2] = fmaf(w, v.z, acc[2]);
        acc[3] = fmaf(w, v.w, acc[3]);
    }
    *(f32x4*)(ctxp + ((size_t)tc * B_ + b) * D_ + d0) = acc;
}

// ---------------- context stage 2: reduce 32 partials ----------
__global__ void context2_kernel(const float* __restrict__ ctxp, float* __restrict__ out) {
    const int i = blockIdx.x * 256 + threadIdx.x;   // grid 128 -> 32768
    float s = 0.f;
#pragma unroll
    for (int tc = 0; tc < 32; ++tc) s += ctxp[(size_t)tc * (B_ * D_) + i];
    out[i] = s;
}

extern "C" void kernel_launch(void* const* d_in, const int* in_sizes, int n_in,
                              void* d_out, int out_size, void* d_ws, size_t ws_size,
                              hipStream_t stream) {
    const float* values = (const float*)d_in[0];
    const float* query  = (const float*)d_in[1];
    const float* mask   = (const float*)d_in[2];
    const float* W1     = (const float*)d_in[3];
    const float* b1     = (const float*)d_in[4];
    const float* W2     = (const float*)d_in[5];
    const float* b2     = (const float*)d_in[6];
    const float* V      = (const float*)d_in[7];
    const float* bV     = (const float*)d_in[8];
    float* out = (float*)d_out;

    char* ws = (char*)d_ws;
    __bf16* W1T   = (__bf16*)(ws + WS_W1T);
    float*  projq = (float*)(ws + WS_PROJQ);
    float*  score = (float*)(ws + WS_SCORE);
    float*  ctxp  = (float*)(ws + WS_CTXP);   // overlaps W1T/projq/score (dead by then)
    __bf16* valb  = (__bf16*)(ws + WS_VALB);

    hipMemsetAsync(score, 0, (size_t)BT_ * sizeof(float), stream);
    w1_transpose_kernel<<<dim3(256), dim3(256), 0, stream>>>(W1, W1T);
    projq_kernel<<<dim3(128), dim3(256), 0, stream>>>(query, W2, b1, b2, projq);
    if (ws_size >= WS_NEEDED) {
        convert_kernel<<<dim3(32768), dim3(256), 0, stream>>>(values, valb);
        score_kernel_bf16<<<dim3(4096), dim3(256), 0, stream>>>(valb, W1T, projq, V, score);
    } else {
        score_kernel_f32<<<dim3(2048), dim3(512), 0, stream>>>(values, W1T, projq, V, score);
    }
    softmax_kernel<<<dim3(32), dim3(256), 0, stream>>>(score, mask, bV, out);
    context1_kernel<<<dim3(1024), dim3(256), 0, stream>>>(values, out + B_ * D_, ctxp);
    context2_kernel<<<dim3(128), dim3(256), 0, stream>>>(ctxp, out);
}